// Round 8
// baseline (492.372 us; speedup 1.0000x reference)
//
#include <hip/hip_runtime.h>
#include <hip/hip_bf16.h>

// LCA sparsifier: 10 iterations of v = 0.9v + 0.1u - 0.1*(a@G); a = soft(v, lam)
// R8: A-side (LDS) software pipeline. Evidence: per-row time invariant ~5ns
// across R2/R6/R7 geometries (B-traffic x1.5, LDS-traffic x2, waves/SIMD 2-4,
// epilogue overlap on/off all null) -> fixed ~600 cyc per kk-step = exposed
// serial chain: addr -> ds_read A (~120cy) -> lgkm wait -> MFMA -> B reload.
// B-depth was null (R6 depth-4) because A re-serializes every step. Fix:
// one-full-step-ahead pipeline on BOTH operands: phase k issues A-reads for
// k+1 and B-reloads for k+2 BEFORE its MFMA cluster -> all operands requested
// ~600cy before use. Named A0_/A1_ register alternation (static idx, rule #20).
//  - geometry unchanged from R7: NRT=3 x512 + NRT=2 x256 blocks (96/64 rows),
//    8 waves, 64-col wave tiles, uu f32 in regs (exact), kk-stagger, setprio.
//  - per-t A preload after barrier (~120cy exposed, once per iter).

typedef __attribute__((ext_vector_type(8))) short bf16x8;
typedef __attribute__((ext_vector_type(16))) float f32x16;

#define ETA 0.1f

__device__ __forceinline__ unsigned short f2bf(float f) {
  union { float f; unsigned u; } x; x.f = f;
  unsigned r = x.u + 0x7fffu + ((x.u >> 16) & 1u);  // round-to-nearest-even
  return (unsigned short)(r >> 16);
}

// ---- prep: G = 0.5(Graw + Graw^T), zero diag, bf16, swizzled into
// mfma_f32_32x32x16_bf16 B-fragment order: B[k][n], lane = (n&31) + 32*((k>>3)&1),
// j = k&7, frag index = (kk*16 + ct)*64 + lane  with kk=k>>4, ct=n>>5.
__global__ void prep_G(const float* __restrict__ Graw, unsigned short* __restrict__ Gb) {
  int idx = blockIdx.x * blockDim.x + threadIdx.x;  // 512*512 elements
  int k = idx >> 9, n = idx & 511;
  float g = 0.5f * (Graw[k * 512 + n] + Graw[n * 512 + k]);
  if (k == n) g = 0.f;
  int kk = k >> 4, ct = n >> 5;
  int lane = (n & 31) + (((k >> 3) & 1) << 5);
  int j = k & 7;
  Gb[((((kk * 16 + ct) * 64) + lane) << 3) + j] = f2bf(g);
}

template <int NRT>  // rows per block = NRT*32
__global__ __launch_bounds__(512, 2) void lca_kernel(
    const float* __restrict__ u_g, const unsigned short* __restrict__ Gb,
    const float* __restrict__ log_lam, float* __restrict__ out, int row_base) {
  // a-buffer: NRT*32 rows x 512 cols bf16, row stride 520 (1040B = 16*65 ->
  // the 8-lane b128 phases of an A-fragment read cover all 8 bank groups;
  // measured 0 conflicts). NRT=3: 99,840 B -> 1 block/CU.
  __shared__ unsigned short sA[NRT * 32 * 520];

  const int tid = threadIdx.x;
  const int lane = tid & 63;
  const int wave = tid >> 6;           // 0..7, owns cols [wave*64, wave*64+64)
  const int R0 = row_base + blockIdx.x * (NRT * 32);
  const int cl = lane & 31;            // col within 32-tile / A-row within tile
  const int rquad = (lane >> 5) * 4;   // C-layout row contribution of lane-half
  const int C0 = wave * 64;
  const int s = (blockIdx.x >> 3) & 31;  // kk stagger across same-XCD blocks

  const float lam = expf(log_lam[0]);

  f32x16 acc[NRT][2];  // wave tile NRT*32 rows x 64 cols; C layout:
                       // col=lane&31, row=(reg&3)+8*(reg>>2)+4*(lane>>5)
  f32x16 uu[NRT][2];   // u kept f32 in registers across all 10 iters (exact)

  // ---- init + epilogue0: load u once; a_1 = soft(0.1*u) -> sA;
  // acc = C-pre-GEMM for t=1: 0.9*(-u) - u = -1.9u.
  #pragma unroll
  for (int rt = 0; rt < NRT; ++rt) {
    #pragma unroll
    for (int ctl = 0; ctl < 2; ++ctl) {
      const int lrow = rt * 32 + rquad;
      const int gcol = C0 + ctl * 32 + cl;
      const float* ub = u_g + (R0 + lrow) * 512 + gcol;
      unsigned short* sa = &sA[lrow * 520 + gcol];
      #pragma unroll
      for (int reg = 0; reg < 16; ++reg) {
        const int rofs = (reg & 3) + 8 * (reg >> 2);
        float uv = ub[rofs * 512];
        uu[rt][ctl][reg] = uv;
        float v = ETA * uv;  // v_1 = 0.1*u
        float av = copysignf(fmaxf(fabsf(v) - lam, 0.f), v);
        sa[rofs * 520] = f2bf(av);
        acc[rt][ctl][reg] = -1.9f * uv;
      }
    }
  }

  const bf16x8* gb = (const bf16x8*)Gb;
  const int bb = (wave * 2) * 64 + lane;  // B-frag base: ct = wave*2 (+64 -> ct+1)

  // ---- prime depth-2(step) B pipeline: slots <- slabs (s+0), (s+1).
  bf16x8 P0a = gb[bb + ((s + 0) & 31) * 1024], P0b = gb[bb + ((s + 0) & 31) * 1024 + 64];
  bf16x8 P1a = gb[bb + ((s + 1) & 31) * 1024], P1b = gb[bb + ((s + 1) & 31) * 1024 + 64];

  __syncthreads();

  // A-fragment: A[m][k], m = cl (row in 32-tile), k = kc*16 + (lane>>5)*8 + j
  const unsigned short* paRow = sA + cl * 520 + ((lane >> 5) << 3);

  #pragma unroll 1
  for (int t = 1; t < 10; ++t) {
    // preload A for step 0 of this iteration (sA was republished at barrier)
    bf16x8 A0_[NRT], A1_[NRT];
    #pragma unroll
    for (int rt = 0; rt < NRT; ++rt)
      A0_[rt] = *(const bf16x8*)(paRow + rt * (32 * 520) + (s & 31) * 16);

    #pragma unroll 1
    for (int kk = 0; kk < 32; kk += 2) {
      // ---- phase 0: prefetch A(kk+1)->A1_, B(kk+2)->P0; consume A0_ x P0
      {
        const int kn = (kk + 1 + s) & 31;
        #pragma unroll
        for (int rt = 0; rt < NRT; ++rt)
          A1_[rt] = *(const bf16x8*)(paRow + rt * (32 * 520) + kn * 16);
        const int kl = (kk + 2 + s) & 31;
        bf16x8 nPa = gb[bb + kl * 1024];
        bf16x8 nPb = gb[bb + kl * 1024 + 64];
        __builtin_amdgcn_s_setprio(1);
        #pragma unroll
        for (int rt = 0; rt < NRT; ++rt) {
          acc[rt][0] = __builtin_amdgcn_mfma_f32_32x32x16_bf16(A0_[rt], P0a, acc[rt][0], 0, 0, 0);
          acc[rt][1] = __builtin_amdgcn_mfma_f32_32x32x16_bf16(A0_[rt], P0b, acc[rt][1], 0, 0, 0);
        }
        __builtin_amdgcn_s_setprio(0);
        P0a = nPa; P0b = nPb;
      }
      // ---- phase 1: prefetch A(kk+2)->A0_ (wraps to slab s at kk=30: a dead
      // read of valid current-buffer data), B(kk+3)->P1; consume A1_ x P1
      {
        const int kn = (kk + 2 + s) & 31;
        #pragma unroll
        for (int rt = 0; rt < NRT; ++rt)
          A0_[rt] = *(const bf16x8*)(paRow + rt * (32 * 520) + kn * 16);
        const int kl = (kk + 3 + s) & 31;
        bf16x8 nPa = gb[bb + kl * 1024];
        bf16x8 nPb = gb[bb + kl * 1024 + 64];
        __builtin_amdgcn_s_setprio(1);
        #pragma unroll
        for (int rt = 0; rt < NRT; ++rt) {
          acc[rt][0] = __builtin_amdgcn_mfma_f32_32x32x16_bf16(A1_[rt], P1a, acc[rt][0], 0, 0, 0);
          acc[rt][1] = __builtin_amdgcn_mfma_f32_32x32x16_bf16(A1_[rt], P1b, acc[rt][1], 0, 0, 0);
        }
        __builtin_amdgcn_s_setprio(0);
        P1a = nPa; P1b = nPb;
      }
    }
    // B wrap-around reloads at kk=30 hit slabs s, s+1 = next t's first two:
    // B pipeline self-primes across t (G constant across iterations).
    __syncthreads();  // all A-reads of this GEMM done before epilogue overwrite
    if (t < 9) {
      // epilogue: a_{t+1} = soft(-ETA*acc) -> sA; acc = 0.9*acc - u
      #pragma unroll
      for (int rt = 0; rt < NRT; ++rt) {
        #pragma unroll
        for (int ctl = 0; ctl < 2; ++ctl) {
          unsigned short* sa = &sA[(rt * 32 + rquad) * 520 + C0 + ctl * 32 + cl];
          #pragma unroll
          for (int reg = 0; reg < 16; ++reg) {
            const int rofs = (reg & 3) + 8 * (reg >> 2);
            float v = -ETA * acc[rt][ctl][reg];
            float av = copysignf(fmaxf(fabsf(v) - lam, 0.f), v);
            sa[rofs * 520] = f2bf(av);
            acc[rt][ctl][reg] = 0.9f * acc[rt][ctl][reg] - uu[rt][ctl][reg];
          }
        }
      }
      __syncthreads();  // publish a_{t+1}
    }
  }

  // ---- final output: a_10 = soft(-ETA * acc)
  #pragma unroll
  for (int rt = 0; rt < NRT; ++rt) {
    #pragma unroll
    for (int ctl = 0; ctl < 2; ++ctl) {
      float* ob = out + (R0 + rt * 32 + rquad) * 512 + C0 + ctl * 32 + cl;
      #pragma unroll
      for (int reg = 0; reg < 16; ++reg) {
        const int rofs = (reg & 3) + 8 * (reg >> 2);
        float v = -ETA * acc[rt][ctl][reg];
        ob[rofs * 512] = copysignf(fmaxf(fabsf(v) - lam, 0.f), v);
      }
    }
  }
}

extern "C" void kernel_launch(void* const* d_in, const int* in_sizes, int n_in,
                              void* d_out, int out_size, void* d_ws, size_t ws_size,
                              hipStream_t stream) {
  const float* u = (const float*)d_in[0];
  const float* Graw = (const float*)d_in[1];
  const float* log_lam = (const float*)d_in[2];
  float* out = (float*)d_out;
  unsigned short* Gb = (unsigned short*)d_ws;  // 512*512*2 = 512 KB scratch

  prep_G<<<dim3(1024), dim3(256), 0, stream>>>(Graw, Gb);
  // 512 blocks x 96 rows + 256 blocks x 64 rows = 65536 rows; 3 blocks/CU total.
  lca_kernel<3><<<dim3(512), dim3(512), 0, stream>>>(u, Gb, log_lam, out, 0);
  lca_kernel<2><<<dim3(256), dim3(512), 0, stream>>>(u, Gb, log_lam, out, 512 * 96);
}